// Round 3
// baseline (1059.233 us; speedup 1.0000x reference)
//
#include <hip/hip_runtime.h>
#include <climits>

// ---------------- wave (64-lane) reductions ----------------
__device__ __forceinline__ float waveMax(float v) {
  #pragma unroll
  for (int o = 32; o > 0; o >>= 1) v = fmaxf(v, __shfl_xor(v, o));
  return v;
}
__device__ __forceinline__ float waveSum(float v) {
  #pragma unroll
  for (int o = 32; o > 0; o >>= 1) v += __shfl_xor(v, o);
  return v;
}

// ---------------- zero counters, seed min/max ----------------
__global__ void k_zero(int* __restrict__ cnt, float* __restrict__ deg,
                       int* __restrict__ gctr, int* __restrict__ mm, int n) {
  int i = blockIdx.x * blockDim.x + threadIdx.x;
  if (i < n) { cnt[i] = 0; deg[i] = 0.f; }
  if (i == 0) { *gctr = 0; mm[0] = INT_MAX; mm[1] = INT_MIN; }
}

// ---------------- min/max over edge_count ----------------
__global__ void k_minmax(const int* __restrict__ ec, int n, int* __restrict__ mm) {
  int i = blockIdx.x * blockDim.x + threadIdx.x;
  int stride = gridDim.x * blockDim.x;
  int vmin = INT_MAX, vmax = INT_MIN;
  for (; i < n; i += stride) {
    int v = ec[i];
    vmin = min(vmin, v);
    vmax = max(vmax, v);
  }
  #pragma unroll
  for (int o = 32; o > 0; o >>= 1) {
    vmin = min(vmin, __shfl_xor(vmin, o));
    vmax = max(vmax, __shfl_xor(vmax, o));
  }
  if ((threadIdx.x & 63) == 0) {
    atomicMin(&mm[0], vmin);
    atomicMax(&mm[1], vmax);
  }
}

// ---------------- histogram: cnt[col]++, deg[col] += ew ----------------
__global__ void k_hist(const int* __restrict__ ecol, const int* __restrict__ ec,
                       const int* __restrict__ mm, int* __restrict__ cnt,
                       float* __restrict__ deg, int nE) {
  int i = blockIdx.x * blockDim.x + threadIdx.x;
  if (i >= nE) return;
  float mn = (float)mm[0];
  float rcp = 1.0f / (float)(mm[1] - mm[0]);
  float ew = ((float)ec[i] - mn) * rcp;
  int c = ecol[i];
  atomicAdd(&cnt[c], 1);
  atomicAdd(&deg[c], ew);
}

// ---------------- segment base offsets via wave scan + one atomic/wave ------
__global__ void k_base(const int* __restrict__ cnt, int* __restrict__ rowptr,
                       int* __restrict__ cursor, int* __restrict__ gctr, int n) {
  int i = blockIdx.x * blockDim.x + threadIdx.x;
  int lane = threadIdx.x & 63;
  int v = (i < n) ? cnt[i] : 0;
  int s = v;
  #pragma unroll
  for (int o = 1; o < 64; o <<= 1) {
    int t = __shfl_up(s, o);
    if (lane >= o) s += t;
  }
  int wtot = __shfl(s, 63);
  int base = 0;
  if (lane == 63) base = atomicAdd(gctr, wtot);
  base = __shfl(base, 63);
  int excl = base + s - v;
  if (i < n) { rowptr[i] = excl; cursor[i] = excl; }
}

// ---------------- dinv = rsqrt(deg + 1) ----------------
__global__ void k_dinv(const float* __restrict__ deg, float* __restrict__ dinv, int n) {
  int i = blockIdx.x * blockDim.x + threadIdx.x;
  if (i < n) dinv[i] = rsqrtf(deg[i] + 1.0f);
}

// ---------------- fill CSR: srcw[p] = {row, ew} ----------------
__global__ void k_fill(const int* __restrict__ erow, const int* __restrict__ ecol,
                       const int* __restrict__ ec, const int* __restrict__ mm,
                       int* __restrict__ cursor, int2* __restrict__ srcw, int nE) {
  int e = blockIdx.x * blockDim.x + threadIdx.x;
  if (e >= nE) return;
  float mn = (float)mm[0];
  float rcp = 1.0f / (float)(mm[1] - mm[0]);
  float ew = ((float)ec[e] - mn) * rcp;
  int c = ecol[e];
  int p = atomicAdd(&cursor[c], 1);
  srcw[p] = make_int2(erow[e], __float_as_int(ew));
}

// ---------------- tiled register-blocked GEMM: [n,K] x [K,64] ----------------
// Block: TPB threads, ROWS=TPB/2 rows per tile. Thread (tr=tid>>4, tc=tid&15)
// computes 8 rows (tr + TRR*i) x 4 cols (tc*4..tc*4+3). A-tile double-buffered
// in LDS (padded stride 36 -> conflict-free), W staged once as [k][tc] float4.
template<int K, int TPB>
__global__ __launch_bounds__(TPB) void k_gemm(const float* __restrict__ A,
                                              const float* __restrict__ W,
                                              float* __restrict__ out, int n) {
  constexpr int ROWS = TPB / 2;
  constexpr int KSTEPS = K / 32;
  constexpr int TRR = TPB / 16;
  __shared__ float4 wlds[K * 16];
  __shared__ float alds[2][ROWS * 36];
  const int tid = threadIdx.x;
  const float4* W4 = (const float4*)W;
  for (int f = tid; f < K * 16; f += TPB) wlds[f] = W4[f];
  const int tr = tid >> 4, tc = tid & 15;
  const int rbase = blockIdx.x * ROWS;

  float4 acc[8];
  #pragma unroll
  for (int i = 0; i < 8; ++i) acc[i] = make_float4(0.f, 0.f, 0.f, 0.f);
  float4 sreg[4];

  auto issue = [&](int kt) {
    #pragma unroll
    for (int j = 0; j < 4; ++j) {
      int f = tid + TPB * j;
      int row = f >> 3, c4 = f & 7;
      int gr = rbase + row; if (gr >= n) gr = n - 1;
      sreg[j] = ((const float4*)(A + (size_t)gr * K))[kt * 8 + c4];
    }
  };
  auto commit = [&](int b) {
    #pragma unroll
    for (int j = 0; j < 4; ++j) {
      int f = tid + TPB * j;
      int row = f >> 3, c4 = f & 7;
      *(float4*)&alds[b][row * 36 + c4 * 4] = sreg[j];
    }
  };

  issue(0); commit(0);
  for (int kt = 0; kt < KSTEPS; ++kt) {
    if (kt + 1 < KSTEPS) issue(kt + 1);
    __syncthreads();
    const float* ab = alds[kt & 1];
    #pragma unroll
    for (int k4 = 0; k4 < 8; ++k4) {
      float4 wv0 = wlds[(kt * 32 + k4 * 4 + 0) * 16 + tc];
      float4 wv1 = wlds[(kt * 32 + k4 * 4 + 1) * 16 + tc];
      float4 wv2 = wlds[(kt * 32 + k4 * 4 + 2) * 16 + tc];
      float4 wv3 = wlds[(kt * 32 + k4 * 4 + 3) * 16 + tc];
      #pragma unroll
      for (int i = 0; i < 8; ++i) {
        float4 av = *(const float4*)&ab[(tr + TRR * i) * 36 + k4 * 4];
        acc[i].x = fmaf(av.x, wv0.x, acc[i].x);
        acc[i].y = fmaf(av.x, wv0.y, acc[i].y);
        acc[i].z = fmaf(av.x, wv0.z, acc[i].z);
        acc[i].w = fmaf(av.x, wv0.w, acc[i].w);
        acc[i].x = fmaf(av.y, wv1.x, acc[i].x);
        acc[i].y = fmaf(av.y, wv1.y, acc[i].y);
        acc[i].z = fmaf(av.y, wv1.z, acc[i].z);
        acc[i].w = fmaf(av.y, wv1.w, acc[i].w);
        acc[i].x = fmaf(av.z, wv2.x, acc[i].x);
        acc[i].y = fmaf(av.z, wv2.y, acc[i].y);
        acc[i].z = fmaf(av.z, wv2.z, acc[i].z);
        acc[i].w = fmaf(av.z, wv2.w, acc[i].w);
        acc[i].x = fmaf(av.w, wv3.x, acc[i].x);
        acc[i].y = fmaf(av.w, wv3.y, acc[i].y);
        acc[i].z = fmaf(av.w, wv3.z, acc[i].z);
        acc[i].w = fmaf(av.w, wv3.w, acc[i].w);
      }
    }
    if (kt + 1 < KSTEPS) commit((kt + 1) & 1);
  }
  #pragma unroll
  for (int i = 0; i < 8; ++i) {
    int row = rbase + tr + TRR * i;
    if (row < n) *(float4*)&out[(size_t)row * 64 + tc * 4] = acc[i];
  }
}

// ---------------- aggregation: lane-parallel metadata + 4-deep gathers ------
template<bool FINAL>
__global__ void k_agg(const int* __restrict__ rowptr, const int* __restrict__ cnt,
                      const int2* __restrict__ srcw, const float* __restrict__ dinv,
                      const float* __restrict__ xw, const float* __restrict__ b,
                      float* __restrict__ outp, int nN) {
  int node = blockIdx.x * (blockDim.x >> 6) + (threadIdx.x >> 6);
  if (node >= nN) return;
  int lane = threadIdx.x & 63;
  float dc = dinv[node];
  float acc = dc * dc * xw[(size_t)node * 64 + lane];
  int s = rowptr[node];
  int m = cnt[node];
  for (int cb = 0; cb < m; cb += 64) {
    int take = min(64, m - cb);
    int rsrc = 0;
    float nrmv = 0.f;
    if (lane < take) {
      int2 rw = srcw[s + cb + lane];
      rsrc = rw.x;
      nrmv = dinv[rw.x] * __int_as_float(rw.y) * dc;
    }
    int j = 0;
    for (; j + 4 <= take; j += 4) {
      int r0 = __shfl(rsrc, j + 0), r1 = __shfl(rsrc, j + 1);
      int r2 = __shfl(rsrc, j + 2), r3 = __shfl(rsrc, j + 3);
      float n0 = __shfl(nrmv, j + 0), n1 = __shfl(nrmv, j + 1);
      float n2 = __shfl(nrmv, j + 2), n3 = __shfl(nrmv, j + 3);
      float v0 = xw[(size_t)r0 * 64 + lane];
      float v1 = xw[(size_t)r1 * 64 + lane];
      float v2 = xw[(size_t)r2 * 64 + lane];
      float v3 = xw[(size_t)r3 * 64 + lane];
      acc = fmaf(n0, v0, acc);
      acc = fmaf(n1, v1, acc);
      acc = fmaf(n2, v2, acc);
      acc = fmaf(n3, v3, acc);
    }
    for (; j < take; ++j) {
      int r = __shfl(rsrc, j);
      float nj = __shfl(nrmv, j);
      acc = fmaf(nj, xw[(size_t)r * 64 + lane], acc);
    }
  }
  float v = acc + b[lane];
  size_t idx = (size_t)node * 64 + lane;
  if (FINAL) {
    outp[idx] = v;
    float mx = waveMax(v);
    float sum = waveSum(expf(v - mx));
    outp[(size_t)nN * 64 + idx] = v - mx - logf(sum);
  } else {
    outp[idx] = fmaxf(v, 0.f);
  }
}

extern "C" void kernel_launch(void* const* d_in, const int* in_sizes, int n_in,
                              void* d_out, int out_size, void* d_ws, size_t ws_size,
                              hipStream_t stream) {
  const float* x  = (const float*)d_in[0];
  const int*   ei = (const int*)d_in[1];
  const int*   ec = (const int*)d_in[2];
  const float* W1 = (const float*)d_in[3];
  const float* b1 = (const float*)d_in[4];
  const float* W2 = (const float*)d_in[5];
  const float* b2 = (const float*)d_in[6];

  int nN = in_sizes[0] / 256;   // 100000
  int nE = in_sizes[2];         // 1600000
  const int* erow = ei;
  const int* ecol = ei + nE;
  int n64 = nN * 64;

  // ---- workspace layout (4B units) ----
  int*   wsi    = (int*)d_ws;
  int*   mm     = wsi;            // 2
  int*   gctr   = wsi + 2;        // 1
  int*   cnt    = wsi + 16;
  int*   rowptr = cnt + nN;
  int*   cursor = rowptr + nN;
  float* deg    = (float*)(cursor + nN);
  float* dinv   = deg + nN;
  int2*  srcw   = (int2*)(dinv + nN);        // 8B aligned (even offset)
  float* xw     = (float*)(srcw + nE);       // [nN,64]
  float* h1     = xw + (size_t)n64;          // [nN,64]
  float* outp   = (float*)d_out;

  // ---- CSR build + normalization ----
  k_zero<<<(nN + 255) / 256, 256, 0, stream>>>(cnt, deg, gctr, mm, nN);
  k_minmax<<<1024, 256, 0, stream>>>(ec, nE, mm);
  k_hist<<<(nE + 255) / 256, 256, 0, stream>>>(ecol, ec, mm, cnt, deg, nE);
  k_base<<<(nN + 255) / 256, 256, 0, stream>>>(cnt, rowptr, cursor, gctr, nN);
  k_dinv<<<(nN + 255) / 256, 256, 0, stream>>>(deg, dinv, nN);
  k_fill<<<(nE + 255) / 256, 256, 0, stream>>>(erow, ecol, ec, mm, cursor, srcw, nE);

  // ---- layer 1 ----
  k_gemm<256, 512><<<(nN + 255) / 256, 512, 0, stream>>>(x, W1, xw, nN);
  k_agg<false><<<(nN + 3) / 4, 256, 0, stream>>>(rowptr, cnt, srcw, dinv, xw, b1, h1, nN);

  // ---- layer 2 ----
  k_gemm<64, 256><<<(nN + 127) / 128, 256, 0, stream>>>(h1, W2, xw, nN);
  k_agg<true><<<(nN + 3) / 4, 256, 0, stream>>>(rowptr, cnt, srcw, dinv, xw, b2, outp, nN);
}

// Round 4
// 637.840 us; speedup vs baseline: 1.6607x; 1.6607x over previous
//
#include <hip/hip_runtime.h>
#include <climits>

// ---------------- wave (64-lane) reductions ----------------
__device__ __forceinline__ float waveMax(float v) {
  #pragma unroll
  for (int o = 32; o > 0; o >>= 1) v = fmaxf(v, __shfl_xor(v, o));
  return v;
}
__device__ __forceinline__ float waveSum(float v) {
  #pragma unroll
  for (int o = 32; o > 0; o >>= 1) v += __shfl_xor(v, o);
  return v;
}

// ---------------- async global->LDS 16B (no VGPR round-trip) ----------------
__device__ __forceinline__ void gload16(const float* g, float* l) {
  __builtin_amdgcn_global_load_lds(
      (const __attribute__((address_space(1))) void*)(g),
      (__attribute__((address_space(3))) void*)(l),
      16, 0, 0);
}

// ---------------- zero counters, seed min/max ----------------
__global__ void k_zero(int* __restrict__ cnt, float* __restrict__ deg,
                       int* __restrict__ gctr, int* __restrict__ mm, int n) {
  int i = blockIdx.x * blockDim.x + threadIdx.x;
  if (i < n) { cnt[i] = 0; deg[i] = 0.f; }
  if (i == 0) { *gctr = 0; mm[0] = INT_MAX; mm[1] = INT_MIN; }
}

// ---------------- min/max over edge_count ----------------
__global__ void k_minmax(const int* __restrict__ ec, int n, int* __restrict__ mm) {
  int i = blockIdx.x * blockDim.x + threadIdx.x;
  int stride = gridDim.x * blockDim.x;
  int vmin = INT_MAX, vmax = INT_MIN;
  for (; i < n; i += stride) {
    int v = ec[i];
    vmin = min(vmin, v);
    vmax = max(vmax, v);
  }
  #pragma unroll
  for (int o = 32; o > 0; o >>= 1) {
    vmin = min(vmin, __shfl_xor(vmin, o));
    vmax = max(vmax, __shfl_xor(vmax, o));
  }
  if ((threadIdx.x & 63) == 0) {
    atomicMin(&mm[0], vmin);
    atomicMax(&mm[1], vmax);
  }
}

// ---------------- histogram: cnt[col]++, deg[col] += ew ----------------
__global__ void k_hist(const int* __restrict__ ecol, const int* __restrict__ ec,
                       const int* __restrict__ mm, int* __restrict__ cnt,
                       float* __restrict__ deg, int nE) {
  int i = blockIdx.x * blockDim.x + threadIdx.x;
  if (i >= nE) return;
  float mn = (float)mm[0];
  float rcp = 1.0f / (float)(mm[1] - mm[0]);
  float ew = ((float)ec[i] - mn) * rcp;
  int c = ecol[i];
  atomicAdd(&cnt[c], 1);
  atomicAdd(&deg[c], ew);
}

// ---------------- segment base offsets via wave scan + one atomic/wave ------
__global__ void k_base(const int* __restrict__ cnt, int* __restrict__ rowptr,
                       int* __restrict__ cursor, int* __restrict__ gctr, int n) {
  int i = blockIdx.x * blockDim.x + threadIdx.x;
  int lane = threadIdx.x & 63;
  int v = (i < n) ? cnt[i] : 0;
  int s = v;
  #pragma unroll
  for (int o = 1; o < 64; o <<= 1) {
    int t = __shfl_up(s, o);
    if (lane >= o) s += t;
  }
  int wtot = __shfl(s, 63);
  int base = 0;
  if (lane == 63) base = atomicAdd(gctr, wtot);
  base = __shfl(base, 63);
  int excl = base + s - v;
  if (i < n) { rowptr[i] = excl; cursor[i] = excl; }
}

// ---------------- dinv = rsqrt(deg + 1) ----------------
__global__ void k_dinv(const float* __restrict__ deg, float* __restrict__ dinv, int n) {
  int i = blockIdx.x * blockDim.x + threadIdx.x;
  if (i < n) dinv[i] = rsqrtf(deg[i] + 1.0f);
}

// ---------------- fill CSR: srcw[p] = {row, ew} ----------------
__global__ void k_fill(const int* __restrict__ erow, const int* __restrict__ ecol,
                       const int* __restrict__ ec, const int* __restrict__ mm,
                       int* __restrict__ cursor, int2* __restrict__ srcw, int nE) {
  int e = blockIdx.x * blockDim.x + threadIdx.x;
  if (e >= nE) return;
  float mn = (float)mm[0];
  float rcp = 1.0f / (float)(mm[1] - mm[0]);
  float ew = ((float)ec[e] - mn) * rcp;
  int c = ecol[e];
  int p = atomicAdd(&cursor[c], 1);
  srcw[p] = make_int2(erow[e], __float_as_int(ew));
}

// ---------------- GEMM: [n,K] x [K,64] -> [n,64] -------------------------
// 256 threads, 128-row tiles. A-tile [128][32]f and W-tile [32][64]f staged
// via global_load_lds (double-buffered, 48 KB total -> 3 blocks/CU).
// Thread (tr=tid>>4, tc=tid&15) computes 8 rows x 4 cols in registers.
// A-tile chunk c4s of row holds global chunk c4s^(row&7): conflict-free
// ds_read_b128 (inverse swizzle applied on the global source address).
template<int K>
__global__ __launch_bounds__(256) void k_gemm(const float* __restrict__ A,
                                              const float* __restrict__ W,
                                              float* __restrict__ out, int n) {
  constexpr int KSTEPS = K / 32;
  __shared__ float atile[2][128 * 32];
  __shared__ float wtile[2][32 * 64];
  const int tid = threadIdx.x;
  const int wv = tid >> 6;
  const int tr = tid >> 4, tc = tid & 15;
  const int rbase = blockIdx.x * 128;

  auto stageA = [&](int kt, int b) {
    #pragma unroll
    for (int r = 0; r < 4; ++r) {
      int f = r * 256 + tid;            // chunk index [0,1024)
      int row = f >> 3, c4s = f & 7;
      int c4 = c4s ^ (row & 7);         // pre-swizzled source chunk
      int gr = rbase + row; if (gr >= n) gr = n - 1;
      const float* g = A + (size_t)gr * K + kt * 32 + c4 * 4;
      float* l = &atile[b][(r * 256 + wv * 64) * 4];   // wave-uniform base
      gload16(g, l);
    }
  };
  auto stageW = [&](int kt, int b) {
    #pragma unroll
    for (int r = 0; r < 2; ++r) {
      int f = r * 256 + tid;            // chunk index [0,512)
      int krow = f >> 4, c4 = f & 15;
      const float* g = W + (size_t)(kt * 32 + krow) * 64 + c4 * 4;
      float* l = &wtile[b][(r * 256 + wv * 64) * 4];
      gload16(g, l);
    }
  };

  float4 acc[8];
  #pragma unroll
  for (int i = 0; i < 8; ++i) acc[i] = make_float4(0.f, 0.f, 0.f, 0.f);

  stageA(0, 0); stageW(0, 0);
  __syncthreads();
  int cur = 0;
  for (int kt = 0; kt < KSTEPS; ++kt) {
    if (kt + 1 < KSTEPS) { stageA(kt + 1, cur ^ 1); stageW(kt + 1, cur ^ 1); }
    const float* ab = atile[cur];
    const float* wb = wtile[cur];
    #pragma unroll
    for (int k4 = 0; k4 < 8; ++k4) {
      float4 wv0 = *(const float4*)&wb[(k4 * 4 + 0) * 64 + tc * 4];
      float4 wv1 = *(const float4*)&wb[(k4 * 4 + 1) * 64 + tc * 4];
      float4 wv2 = *(const float4*)&wb[(k4 * 4 + 2) * 64 + tc * 4];
      float4 wv3 = *(const float4*)&wb[(k4 * 4 + 3) * 64 + tc * 4];
      #pragma unroll
      for (int i = 0; i < 8; ++i) {
        int row = tr + 16 * i;
        float4 av = *(const float4*)&ab[row * 32 + ((k4 ^ (row & 7)) * 4)];
        acc[i].x = fmaf(av.x, wv0.x, acc[i].x);
        acc[i].y = fmaf(av.x, wv0.y, acc[i].y);
        acc[i].z = fmaf(av.x, wv0.z, acc[i].z);
        acc[i].w = fmaf(av.x, wv0.w, acc[i].w);
        acc[i].x = fmaf(av.y, wv1.x, acc[i].x);
        acc[i].y = fmaf(av.y, wv1.y, acc[i].y);
        acc[i].z = fmaf(av.y, wv1.z, acc[i].z);
        acc[i].w = fmaf(av.y, wv1.w, acc[i].w);
        acc[i].x = fmaf(av.z, wv2.x, acc[i].x);
        acc[i].y = fmaf(av.z, wv2.y, acc[i].y);
        acc[i].z = fmaf(av.z, wv2.z, acc[i].z);
        acc[i].w = fmaf(av.z, wv2.w, acc[i].w);
        acc[i].x = fmaf(av.w, wv3.x, acc[i].x);
        acc[i].y = fmaf(av.w, wv3.y, acc[i].y);
        acc[i].z = fmaf(av.w, wv3.z, acc[i].z);
        acc[i].w = fmaf(av.w, wv3.w, acc[i].w);
      }
    }
    __syncthreads();   // drains vmcnt -> next tile ready; reads of cur done
    cur ^= 1;
  }
  #pragma unroll
  for (int i = 0; i < 8; ++i) {
    int row = rbase + tr + 16 * i;
    if (row < n) *(float4*)&out[(size_t)row * 64 + tc * 4] = acc[i];
  }
}

// ---------------- aggregation: lane-parallel metadata + 4-deep gathers ------
template<bool FINAL>
__global__ void k_agg(const int* __restrict__ rowptr, const int* __restrict__ cnt,
                      const int2* __restrict__ srcw, const float* __restrict__ dinv,
                      const float* __restrict__ xw, const float* __restrict__ b,
                      float* __restrict__ outp, int nN) {
  int node = blockIdx.x * (blockDim.x >> 6) + (threadIdx.x >> 6);
  if (node >= nN) return;
  int lane = threadIdx.x & 63;
  float dc = dinv[node];
  float acc = dc * dc * xw[(size_t)node * 64 + lane];
  int s = rowptr[node];
  int m = cnt[node];
  for (int cb = 0; cb < m; cb += 64) {
    int take = min(64, m - cb);
    int rsrc = 0;
    float nrmv = 0.f;
    if (lane < take) {
      int2 rw = srcw[s + cb + lane];
      rsrc = rw.x;
      nrmv = dinv[rw.x] * __int_as_float(rw.y) * dc;
    }
    int j = 0;
    for (; j + 4 <= take; j += 4) {
      int r0 = __shfl(rsrc, j + 0), r1 = __shfl(rsrc, j + 1);
      int r2 = __shfl(rsrc, j + 2), r3 = __shfl(rsrc, j + 3);
      float n0 = __shfl(nrmv, j + 0), n1 = __shfl(nrmv, j + 1);
      float n2 = __shfl(nrmv, j + 2), n3 = __shfl(nrmv, j + 3);
      float v0 = xw[(size_t)r0 * 64 + lane];
      float v1 = xw[(size_t)r1 * 64 + lane];
      float v2 = xw[(size_t)r2 * 64 + lane];
      float v3 = xw[(size_t)r3 * 64 + lane];
      acc = fmaf(n0, v0, acc);
      acc = fmaf(n1, v1, acc);
      acc = fmaf(n2, v2, acc);
      acc = fmaf(n3, v3, acc);
    }
    for (; j < take; ++j) {
      int r = __shfl(rsrc, j);
      float nj = __shfl(nrmv, j);
      acc = fmaf(nj, xw[(size_t)r * 64 + lane], acc);
    }
  }
  float v = acc + b[lane];
  size_t idx = (size_t)node * 64 + lane;
  if (FINAL) {
    outp[idx] = v;
    float mx = waveMax(v);
    float sum = waveSum(expf(v - mx));
    outp[(size_t)nN * 64 + idx] = v - mx - logf(sum);
  } else {
    outp[idx] = fmaxf(v, 0.f);
  }
}

extern "C" void kernel_launch(void* const* d_in, const int* in_sizes, int n_in,
                              void* d_out, int out_size, void* d_ws, size_t ws_size,
                              hipStream_t stream) {
  const float* x  = (const float*)d_in[0];
  const int*   ei = (const int*)d_in[1];
  const int*   ec = (const int*)d_in[2];
  const float* W1 = (const float*)d_in[3];
  const float* b1 = (const float*)d_in[4];
  const float* W2 = (const float*)d_in[5];
  const float* b2 = (const float*)d_in[6];

  int nN = in_sizes[0] / 256;   // 100000
  int nE = in_sizes[2];         // 1600000
  const int* erow = ei;
  const int* ecol = ei + nE;
  int n64 = nN * 64;

  // ---- workspace layout (4B units) ----
  int*   wsi    = (int*)d_ws;
  int*   mm     = wsi;            // 2
  int*   gctr   = wsi + 2;        // 1
  int*   cnt    = wsi + 16;
  int*   rowptr = cnt + nN;
  int*   cursor = rowptr + nN;
  float* deg    = (float*)(cursor + nN);
  float* dinv   = deg + nN;
  int2*  srcw   = (int2*)(dinv + nN);        // 8B aligned (even offset)
  float* xw     = (float*)(srcw + nE);       // [nN,64]
  float* h1     = xw + (size_t)n64;          // [nN,64]
  float* outp   = (float*)d_out;

  // ---- CSR build + normalization ----
  k_zero<<<(nN + 255) / 256, 256, 0, stream>>>(cnt, deg, gctr, mm, nN);
  k_minmax<<<1024, 256, 0, stream>>>(ec, nE, mm);
  k_hist<<<(nE + 255) / 256, 256, 0, stream>>>(ecol, ec, mm, cnt, deg, nE);
  k_base<<<(nN + 255) / 256, 256, 0, stream>>>(cnt, rowptr, cursor, gctr, nN);
  k_dinv<<<(nN + 255) / 256, 256, 0, stream>>>(deg, dinv, nN);
  k_fill<<<(nE + 255) / 256, 256, 0, stream>>>(erow, ecol, ec, mm, cursor, srcw, nE);

  // ---- layer 1 ----
  k_gemm<256><<<(nN + 127) / 128, 256, 0, stream>>>(x, W1, xw, nN);
  k_agg<false><<<(nN + 3) / 4, 256, 0, stream>>>(rowptr, cnt, srcw, dinv, xw, b1, h1, nN);

  // ---- layer 2 ----
  k_gemm<64><<<(nN + 127) / 128, 256, 0, stream>>>(h1, W2, xw, nN);
  k_agg<true><<<(nN + 3) / 4, 256, 0, stream>>>(rowptr, cnt, srcw, dinv, xw, b2, outp, nN);
}

// Round 5
// 477.517 us; speedup vs baseline: 2.2182x; 1.3357x over previous
//
#include <hip/hip_runtime.h>
#include <climits>

#define DEG_SCALE 1048576.0f   // 2^20 fixed-point for packed degree
#define DEG_MASK  ((1ULL << 44) - 1)

// ---------------- wave (64-lane) reductions ----------------
__device__ __forceinline__ float waveMax(float v) {
  #pragma unroll
  for (int o = 32; o > 0; o >>= 1) v = fmaxf(v, __shfl_xor(v, o));
  return v;
}
__device__ __forceinline__ float waveSum(float v) {
  #pragma unroll
  for (int o = 32; o > 0; o >>= 1) v += __shfl_xor(v, o);
  return v;
}

// ---------------- async global->LDS 16B (no VGPR round-trip) ----------------
__device__ __forceinline__ void gload16(const float* g, float* l) {
  __builtin_amdgcn_global_load_lds(
      (const __attribute__((address_space(1))) void*)(g),
      (__attribute__((address_space(3))) void*)(l),
      16, 0, 0);
}

// ---------------- zero packed histogram, seed min/max ----------------
__global__ void k_zero(unsigned long long* __restrict__ packed,
                       int* __restrict__ gctr, int* __restrict__ mm, int n) {
  int i = blockIdx.x * blockDim.x + threadIdx.x;
  if (i < n) packed[i] = 0ULL;
  if (i == 0) { *gctr = 0; mm[0] = INT_MAX; mm[1] = INT_MIN; }
}

// ---------------- min/max over edge_count ----------------
__global__ void k_minmax(const int* __restrict__ ec, int n, int* __restrict__ mm) {
  int i = blockIdx.x * blockDim.x + threadIdx.x;
  int stride = gridDim.x * blockDim.x;
  int vmin = INT_MAX, vmax = INT_MIN;
  for (; i < n; i += stride) {
    int v = ec[i];
    vmin = min(vmin, v);
    vmax = max(vmax, v);
  }
  #pragma unroll
  for (int o = 32; o > 0; o >>= 1) {
    vmin = min(vmin, __shfl_xor(vmin, o));
    vmax = max(vmax, __shfl_xor(vmax, o));
  }
  if ((threadIdx.x & 63) == 0) {
    atomicMin(&mm[0], vmin);
    atomicMax(&mm[1], vmax);
  }
}

// ---------------- histogram: one packed u64 atomic per edge ----------------
// packed[c] += (1<<44) | fx(ew). Returned old count-field = edge's rank.
__global__ void k_hist(const int* __restrict__ ecol, const int* __restrict__ ec,
                       const int* __restrict__ mm,
                       unsigned long long* __restrict__ packed,
                       int* __restrict__ rank, int nE) {
  int i = blockIdx.x * blockDim.x + threadIdx.x;
  if (i >= nE) return;
  float mn = (float)mm[0];
  float rcp = 1.0f / (float)(mm[1] - mm[0]);
  float ew = ((float)ec[i] - mn) * rcp;
  unsigned long long fx = (unsigned long long)__float2uint_rn(ew * DEG_SCALE);
  unsigned long long old =
      atomicAdd(&packed[ecol[i]], (1ULL << 44) | fx);
  rank[i] = (int)(old >> 44);
}

// ---------------- rowptr scan + dinv from packed ----------------
__global__ void k_base(const unsigned long long* __restrict__ packed,
                       int* __restrict__ rowptr, float* __restrict__ dinv,
                       int* __restrict__ gctr, int n) {
  int i = blockIdx.x * blockDim.x + threadIdx.x;
  int lane = threadIdx.x & 63;
  unsigned long long pk = (i < n) ? packed[i] : 0ULL;
  int v = (int)(pk >> 44);
  if (i < n) {
    float deg = (float)(pk & DEG_MASK) * (1.0f / DEG_SCALE);
    dinv[i] = rsqrtf(deg + 1.0f);
  }
  int s = v;
  #pragma unroll
  for (int o = 1; o < 64; o <<= 1) {
    int t = __shfl_up(s, o);
    if (lane >= o) s += t;
  }
  int wtot = __shfl(s, 63);
  int base = 0;
  if (lane == 63) base = atomicAdd(gctr, wtot);
  base = __shfl(base, 63);
  if (i < n) rowptr[i] = base + s - v;
}

// ---------------- fill CSR without atomics: p = rowptr[c] + rank[e] --------
__global__ void k_fill(const int* __restrict__ erow, const int* __restrict__ ecol,
                       const int* __restrict__ ec, const int* __restrict__ mm,
                       const int* __restrict__ rowptr, const int* __restrict__ rank,
                       int2* __restrict__ srcw, int nE) {
  int e = blockIdx.x * blockDim.x + threadIdx.x;
  if (e >= nE) return;
  float mn = (float)mm[0];
  float rcp = 1.0f / (float)(mm[1] - mm[0]);
  float ew = ((float)ec[e] - mn) * rcp;
  int p = rowptr[ecol[e]] + rank[e];
  srcw[p] = make_int2(erow[e], __float_as_int(ew));
}

// ---------------- GEMM: [n,K] x [K,64] -> [n,64] -------------------------
template<int K>
__global__ __launch_bounds__(256) void k_gemm(const float* __restrict__ A,
                                              const float* __restrict__ W,
                                              float* __restrict__ out, int n) {
  constexpr int KSTEPS = K / 32;
  __shared__ float atile[2][128 * 32];
  __shared__ float wtile[2][32 * 64];
  const int tid = threadIdx.x;
  const int wv = tid >> 6;
  const int tr = tid >> 4, tc = tid & 15;
  const int rbase = blockIdx.x * 128;

  auto stageA = [&](int kt, int b) {
    #pragma unroll
    for (int r = 0; r < 4; ++r) {
      int f = r * 256 + tid;            // chunk index [0,1024)
      int row = f >> 3, c4s = f & 7;
      int c4 = c4s ^ (row & 7);         // pre-swizzled source chunk
      int gr = rbase + row; if (gr >= n) gr = n - 1;
      const float* g = A + (size_t)gr * K + kt * 32 + c4 * 4;
      float* l = &atile[b][(r * 256 + wv * 64) * 4];   // wave-uniform base
      gload16(g, l);
    }
  };
  auto stageW = [&](int kt, int b) {
    #pragma unroll
    for (int r = 0; r < 2; ++r) {
      int f = r * 256 + tid;            // chunk index [0,512)
      int krow = f >> 4, c4 = f & 15;
      const float* g = W + (size_t)(kt * 32 + krow) * 64 + c4 * 4;
      float* l = &wtile[b][(r * 256 + wv * 64) * 4];
      gload16(g, l);
    }
  };

  float4 acc[8];
  #pragma unroll
  for (int i = 0; i < 8; ++i) acc[i] = make_float4(0.f, 0.f, 0.f, 0.f);

  stageA(0, 0); stageW(0, 0);
  __syncthreads();
  int cur = 0;
  for (int kt = 0; kt < KSTEPS; ++kt) {
    if (kt + 1 < KSTEPS) { stageA(kt + 1, cur ^ 1); stageW(kt + 1, cur ^ 1); }
    const float* ab = atile[cur];
    const float* wb = wtile[cur];
    #pragma unroll
    for (int k4 = 0; k4 < 8; ++k4) {
      float4 wv0 = *(const float4*)&wb[(k4 * 4 + 0) * 64 + tc * 4];
      float4 wv1 = *(const float4*)&wb[(k4 * 4 + 1) * 64 + tc * 4];
      float4 wv2 = *(const float4*)&wb[(k4 * 4 + 2) * 64 + tc * 4];
      float4 wv3 = *(const float4*)&wb[(k4 * 4 + 3) * 64 + tc * 4];
      #pragma unroll
      for (int i = 0; i < 8; ++i) {
        int row = tr + 16 * i;
        float4 av = *(const float4*)&ab[row * 32 + ((k4 ^ (row & 7)) * 4)];
        acc[i].x = fmaf(av.x, wv0.x, acc[i].x);
        acc[i].y = fmaf(av.x, wv0.y, acc[i].y);
        acc[i].z = fmaf(av.x, wv0.z, acc[i].z);
        acc[i].w = fmaf(av.x, wv0.w, acc[i].w);
        acc[i].x = fmaf(av.y, wv1.x, acc[i].x);
        acc[i].y = fmaf(av.y, wv1.y, acc[i].y);
        acc[i].z = fmaf(av.y, wv1.z, acc[i].z);
        acc[i].w = fmaf(av.y, wv1.w, acc[i].w);
        acc[i].x = fmaf(av.z, wv2.x, acc[i].x);
        acc[i].y = fmaf(av.z, wv2.y, acc[i].y);
        acc[i].z = fmaf(av.z, wv2.z, acc[i].z);
        acc[i].w = fmaf(av.z, wv2.w, acc[i].w);
        acc[i].x = fmaf(av.w, wv3.x, acc[i].x);
        acc[i].y = fmaf(av.w, wv3.y, acc[i].y);
        acc[i].z = fmaf(av.w, wv3.z, acc[i].z);
        acc[i].w = fmaf(av.w, wv3.w, acc[i].w);
      }
    }
    __syncthreads();
    cur ^= 1;
  }
  #pragma unroll
  for (int i = 0; i < 8; ++i) {
    int row = rbase + tr + 16 * i;
    if (row < n) *(float4*)&out[(size_t)row * 64 + tc * 4] = acc[i];
  }
}

// ---------------- aggregation: lane-parallel metadata + 4-deep gathers ------
template<bool FINAL>
__global__ void k_agg(const int* __restrict__ rowptr,
                      const unsigned long long* __restrict__ packed,
                      const int2* __restrict__ srcw, const float* __restrict__ dinv,
                      const float* __restrict__ xw, const float* __restrict__ b,
                      float* __restrict__ outp, int nN) {
  int node = blockIdx.x * (blockDim.x >> 6) + (threadIdx.x >> 6);
  if (node >= nN) return;
  int lane = threadIdx.x & 63;
  float dc = dinv[node];
  float acc = dc * dc * xw[(size_t)node * 64 + lane];
  int s = rowptr[node];
  int m = (int)(packed[node] >> 44);
  for (int cb = 0; cb < m; cb += 64) {
    int take = min(64, m - cb);
    int rsrc = 0;
    float nrmv = 0.f;
    if (lane < take) {
      int2 rw = srcw[s + cb + lane];
      rsrc = rw.x;
      nrmv = dinv[rw.x] * __int_as_float(rw.y) * dc;
    }
    int j = 0;
    for (; j + 4 <= take; j += 4) {
      int r0 = __shfl(rsrc, j + 0), r1 = __shfl(rsrc, j + 1);
      int r2 = __shfl(rsrc, j + 2), r3 = __shfl(rsrc, j + 3);
      float n0 = __shfl(nrmv, j + 0), n1 = __shfl(nrmv, j + 1);
      float n2 = __shfl(nrmv, j + 2), n3 = __shfl(nrmv, j + 3);
      float v0 = xw[(size_t)r0 * 64 + lane];
      float v1 = xw[(size_t)r1 * 64 + lane];
      float v2 = xw[(size_t)r2 * 64 + lane];
      float v3 = xw[(size_t)r3 * 64 + lane];
      acc = fmaf(n0, v0, acc);
      acc = fmaf(n1, v1, acc);
      acc = fmaf(n2, v2, acc);
      acc = fmaf(n3, v3, acc);
    }
    for (; j < take; ++j) {
      int r = __shfl(rsrc, j);
      float nj = __shfl(nrmv, j);
      acc = fmaf(nj, xw[(size_t)r * 64 + lane], acc);
    }
  }
  float v = acc + b[lane];
  size_t idx = (size_t)node * 64 + lane;
  if (FINAL) {
    outp[idx] = v;
    float mx = waveMax(v);
    float sum = waveSum(expf(v - mx));
    outp[(size_t)nN * 64 + idx] = v - mx - logf(sum);
  } else {
    outp[idx] = fmaxf(v, 0.f);
  }
}

extern "C" void kernel_launch(void* const* d_in, const int* in_sizes, int n_in,
                              void* d_out, int out_size, void* d_ws, size_t ws_size,
                              hipStream_t stream) {
  const float* x  = (const float*)d_in[0];
  const int*   ei = (const int*)d_in[1];
  const int*   ec = (const int*)d_in[2];
  const float* W1 = (const float*)d_in[3];
  const float* b1 = (const float*)d_in[4];
  const float* W2 = (const float*)d_in[5];
  const float* b2 = (const float*)d_in[6];

  int nN = in_sizes[0] / 256;   // 100000
  int nE = in_sizes[2];         // 1600000
  const int* erow = ei;
  const int* ecol = ei + nE;
  int n64 = nN * 64;

  // ---- workspace layout (4B units) ----
  int* wsi = (int*)d_ws;
  int* mm   = wsi;                                  // 2
  int* gctr = wsi + 2;                              // 1
  unsigned long long* packed = (unsigned long long*)(wsi + 16);   // nN u64
  int*   rowptr = wsi + 16 + 2 * nN;
  float* dinv   = (float*)(rowptr + nN);
  int2*  srcw   = (int2*)(dinv + nN);               // even 4B offset -> 8B ok
  float* xw     = (float*)(srcw + nE);              // [nN,64]
  int*   rank   = (int*)xw;                         // aliases xw (dead at gemm1)
  float* h1     = xw + (size_t)n64;                 // [nN,64]
  float* outp   = (float*)d_out;

  // ---- CSR build + normalization ----
  k_zero<<<(nN + 255) / 256, 256, 0, stream>>>(packed, gctr, mm, nN);
  k_minmax<<<1024, 256, 0, stream>>>(ec, nE, mm);
  k_hist<<<(nE + 255) / 256, 256, 0, stream>>>(ecol, ec, mm, packed, rank, nE);
  k_base<<<(nN + 255) / 256, 256, 0, stream>>>(packed, rowptr, dinv, gctr, nN);
  k_fill<<<(nE + 255) / 256, 256, 0, stream>>>(erow, ecol, ec, mm, rowptr, rank, srcw, nE);

  // ---- layer 1 ----
  k_gemm<256><<<(nN + 127) / 128, 256, 0, stream>>>(x, W1, xw, nN);
  k_agg<false><<<(nN + 3) / 4, 256, 0, stream>>>(rowptr, packed, srcw, dinv, xw, b1, h1, nN);

  // ---- layer 2 ----
  k_gemm<64><<<(nN + 127) / 128, 256, 0, stream>>>(h1, W2, xw, nN);
  k_agg<true><<<(nN + 3) / 4, 256, 0, stream>>>(rowptr, packed, srcw, dinv, xw, b2, outp, nN);
}

// Round 6
// 387.550 us; speedup vs baseline: 2.7332x; 1.2321x over previous
//
#include <hip/hip_runtime.h>
#include <climits>

#define CNT_SHIFT 44
#define SUM_MASK  ((1ULL << 44) - 1)

// ---------------- async global->LDS 16B (no VGPR round-trip) ----------------
__device__ __forceinline__ void gload16(const float* g, float* l) {
  __builtin_amdgcn_global_load_lds(
      (const __attribute__((address_space(1))) void*)(g),
      (__attribute__((address_space(3))) void*)(l),
      16, 0, 0);
}

// ---------------- zero packed histogram, seed min/max ----------------
__global__ void k_zero(unsigned long long* __restrict__ packed,
                       int* __restrict__ gctr, int* __restrict__ mm, int n) {
  int i = blockIdx.x * blockDim.x + threadIdx.x;
  if (i < n) packed[i] = 0ULL;
  if (i == 0) { *gctr = 0; mm[0] = INT_MAX; mm[1] = INT_MIN; }
}

// ---------------- min/max: block-reduced, 2 atomics per block ----------------
__global__ void k_minmax(const int* __restrict__ ec, int n, int* __restrict__ mm) {
  __shared__ int smin[4], smax[4];
  int i = blockIdx.x * blockDim.x + threadIdx.x;
  int stride = gridDim.x * blockDim.x;
  int vmin = INT_MAX, vmax = INT_MIN;
  for (; i < n; i += stride) {
    int v = ec[i];
    vmin = min(vmin, v);
    vmax = max(vmax, v);
  }
  #pragma unroll
  for (int o = 32; o > 0; o >>= 1) {
    vmin = min(vmin, __shfl_xor(vmin, o));
    vmax = max(vmax, __shfl_xor(vmax, o));
  }
  int wid = threadIdx.x >> 6;
  if ((threadIdx.x & 63) == 0) { smin[wid] = vmin; smax[wid] = vmax; }
  __syncthreads();
  if (threadIdx.x == 0) {
    #pragma unroll
    for (int w = 1; w < 4; ++w) {
      vmin = min(vmin, smin[w]);
      vmax = max(vmax, smax[w]);
    }
    atomicMin(&mm[0], vmin);
    atomicMax(&mm[1], vmax);
  }
}

// ---------------- histogram: one packed u64 atomic per edge ----------------
// packed[c] += (1<<44) | raw_ec. Returned old count-field = edge's rank.
// (raw sum: max 1.6e9 << 2^44; no min/max dependency, no quantization)
__global__ void k_hist(const int* __restrict__ ecol, const int* __restrict__ ec,
                       unsigned long long* __restrict__ packed,
                       int* __restrict__ rank, int nE) {
  int i = blockIdx.x * blockDim.x + threadIdx.x;
  if (i >= nE) return;
  unsigned long long old =
      atomicAdd(&packed[ecol[i]], (1ULL << CNT_SHIFT) | (unsigned long long)(unsigned)ec[i]);
  rank[i] = (int)(old >> CNT_SHIFT);
}

// ---------------- rowptr scan + dinv from packed ----------------
__global__ void k_base(const unsigned long long* __restrict__ packed,
                       const int* __restrict__ mm,
                       int* __restrict__ rowptr, float* __restrict__ dinv,
                       int* __restrict__ gctr, int n) {
  int i = blockIdx.x * blockDim.x + threadIdx.x;
  int lane = threadIdx.x & 63;
  unsigned long long pk = (i < n) ? packed[i] : 0ULL;
  int v = (int)(pk >> CNT_SHIFT);
  if (i < n) {
    float mn = (float)mm[0];
    float rcp = 1.0f / (float)(mm[1] - mm[0]);
    // deg = sum over edges of (ec - mn)*rcp = (sum_ec - cnt*mn)*rcp
    float deg = ((float)(pk & SUM_MASK) - (float)v * mn) * rcp;
    dinv[i] = rsqrtf(deg + 1.0f);
  }
  int s = v;
  #pragma unroll
  for (int o = 1; o < 64; o <<= 1) {
    int t = __shfl_up(s, o);
    if (lane >= o) s += t;
  }
  int wtot = __shfl(s, 63);
  int base = 0;
  if (lane == 63) base = atomicAdd(gctr, wtot);
  base = __shfl(base, 63);
  if (i < n) rowptr[i] = base + s - v;
}

// ---------------- fill CSR without atomics: p = rowptr[c] + rank[e] --------
__global__ void k_fill(const int* __restrict__ erow, const int* __restrict__ ecol,
                       const int* __restrict__ ec, const int* __restrict__ mm,
                       const int* __restrict__ rowptr, const int* __restrict__ rank,
                       int2* __restrict__ srcw, int nE) {
  int e = blockIdx.x * blockDim.x + threadIdx.x;
  if (e >= nE) return;
  float mn = (float)mm[0];
  float rcp = 1.0f / (float)(mm[1] - mm[0]);
  float ew = ((float)ec[e] - mn) * rcp;
  int p = rowptr[ecol[e]] + rank[e];
  srcw[p] = make_int2(erow[e], __float_as_int(ew));
}

// ---------------- GEMM: [n,K] x [K,64] -> [n,64] -------------------------
template<int K>
__global__ __launch_bounds__(256) void k_gemm(const float* __restrict__ A,
                                              const float* __restrict__ W,
                                              float* __restrict__ out, int n) {
  constexpr int KSTEPS = K / 32;
  __shared__ float atile[2][128 * 32];
  __shared__ float wtile[2][32 * 64];
  const int tid = threadIdx.x;
  const int wv = tid >> 6;
  const int tr = tid >> 4, tc = tid & 15;
  const int rbase = blockIdx.x * 128;

  auto stageA = [&](int kt, int b) {
    #pragma unroll
    for (int r = 0; r < 4; ++r) {
      int f = r * 256 + tid;            // chunk index [0,1024)
      int row = f >> 3, c4s = f & 7;
      int c4 = c4s ^ (row & 7);         // pre-swizzled source chunk
      int gr = rbase + row; if (gr >= n) gr = n - 1;
      const float* g = A + (size_t)gr * K + kt * 32 + c4 * 4;
      float* l = &atile[b][(r * 256 + wv * 64) * 4];   // wave-uniform base
      gload16(g, l);
    }
  };
  auto stageW = [&](int kt, int b) {
    #pragma unroll
    for (int r = 0; r < 2; ++r) {
      int f = r * 256 + tid;            // chunk index [0,512)
      int krow = f >> 4, c4 = f & 15;
      const float* g = W + (size_t)(kt * 32 + krow) * 64 + c4 * 4;
      float* l = &wtile[b][(r * 256 + wv * 64) * 4];
      gload16(g, l);
    }
  };

  float4 acc[8];
  #pragma unroll
  for (int i = 0; i < 8; ++i) acc[i] = make_float4(0.f, 0.f, 0.f, 0.f);

  stageA(0, 0); stageW(0, 0);
  __syncthreads();
  int cur = 0;
  for (int kt = 0; kt < KSTEPS; ++kt) {
    if (kt + 1 < KSTEPS) { stageA(kt + 1, cur ^ 1); stageW(kt + 1, cur ^ 1); }
    const float* ab = atile[cur];
    const float* wb = wtile[cur];
    #pragma unroll
    for (int k4 = 0; k4 < 8; ++k4) {
      float4 wv0 = *(const float4*)&wb[(k4 * 4 + 0) * 64 + tc * 4];
      float4 wv1 = *(const float4*)&wb[(k4 * 4 + 1) * 64 + tc * 4];
      float4 wv2 = *(const float4*)&wb[(k4 * 4 + 2) * 64 + tc * 4];
      float4 wv3 = *(const float4*)&wb[(k4 * 4 + 3) * 64 + tc * 4];
      #pragma unroll
      for (int i = 0; i < 8; ++i) {
        int row = tr + 16 * i;
        float4 av = *(const float4*)&ab[row * 32 + ((k4 ^ (row & 7)) * 4)];
        acc[i].x = fmaf(av.x, wv0.x, acc[i].x);
        acc[i].y = fmaf(av.x, wv0.y, acc[i].y);
        acc[i].z = fmaf(av.x, wv0.z, acc[i].z);
        acc[i].w = fmaf(av.x, wv0.w, acc[i].w);
        acc[i].x = fmaf(av.y, wv1.x, acc[i].x);
        acc[i].y = fmaf(av.y, wv1.y, acc[i].y);
        acc[i].z = fmaf(av.y, wv1.z, acc[i].z);
        acc[i].w = fmaf(av.y, wv1.w, acc[i].w);
        acc[i].x = fmaf(av.z, wv2.x, acc[i].x);
        acc[i].y = fmaf(av.z, wv2.y, acc[i].y);
        acc[i].z = fmaf(av.z, wv2.z, acc[i].z);
        acc[i].w = fmaf(av.z, wv2.w, acc[i].w);
        acc[i].x = fmaf(av.w, wv3.x, acc[i].x);
        acc[i].y = fmaf(av.w, wv3.y, acc[i].y);
        acc[i].z = fmaf(av.w, wv3.z, acc[i].z);
        acc[i].w = fmaf(av.w, wv3.w, acc[i].w);
      }
    }
    __syncthreads();
    cur ^= 1;
  }
  #pragma unroll
  for (int i = 0; i < 8; ++i) {
    int row = rbase + tr + 16 * i;
    if (row < n) *(float4*)&out[(size_t)row * 64 + tc * 4] = acc[i];
  }
}

// ---------------- aggregation: float4 gathers, 4 edges in flight per wave ---
// Lane l: edge-group grp=l>>4, float4 column sub=l&15. Each load instruction
// issues 4 independent 256B row-gathers. Group accumulators combined via
// shfl_xor(16,32); self-loop + bias added post-reduction; lanes 0-15 store.
template<bool FINAL>
__global__ void k_agg(const int* __restrict__ rowptr,
                      const unsigned long long* __restrict__ packed,
                      const int2* __restrict__ srcw, const float* __restrict__ dinv,
                      const float* __restrict__ xw, const float* __restrict__ b,
                      float* __restrict__ outp, int nN) {
  int node = blockIdx.x * (blockDim.x >> 6) + (threadIdx.x >> 6);
  if (node >= nN) return;
  int lane = threadIdx.x & 63;
  int grp = lane >> 4, sub = lane & 15;
  float dc = dinv[node];
  const float4* xw4 = (const float4*)xw;
  float4 acc = make_float4(0.f, 0.f, 0.f, 0.f);
  int s = rowptr[node];
  int m = (int)(packed[node] >> CNT_SHIFT);
  for (int cb = 0; cb < m; cb += 64) {
    int take = min(64, m - cb);
    int rsrc = 0;
    float nrmv = 0.f;
    if (lane < take) {
      int2 rw = srcw[s + cb + lane];
      rsrc = rw.x;
      nrmv = dinv[rw.x] * __int_as_float(rw.y) * dc;
    }
    for (int j = 0; j < take; j += 4) {
      int jj = j + grp;                    // <= 63 always
      int r = __shfl(rsrc, jj);
      float nv = __shfl(nrmv, jj);         // 0 for padded jj >= take
      float4 v = xw4[(size_t)r * 16 + sub];
      acc.x = fmaf(nv, v.x, acc.x);
      acc.y = fmaf(nv, v.y, acc.y);
      acc.z = fmaf(nv, v.z, acc.z);
      acc.w = fmaf(nv, v.w, acc.w);
    }
  }
  // combine the 4 edge-groups: lanes l, l^16, l^32, l^48 hold partials
  #pragma unroll
  for (int o = 16; o <= 32; o <<= 1) {
    acc.x += __shfl_xor(acc.x, o);
    acc.y += __shfl_xor(acc.y, o);
    acc.z += __shfl_xor(acc.z, o);
    acc.w += __shfl_xor(acc.w, o);
  }
  // self-loop + bias (all lanes replicate; row load broadcasts)
  float4 sv = xw4[(size_t)node * 16 + sub];
  float4 bv = ((const float4*)b)[sub];
  float dcc = dc * dc;
  float4 v4;
  v4.x = acc.x + dcc * sv.x + bv.x;
  v4.y = acc.y + dcc * sv.y + bv.y;
  v4.z = acc.z + dcc * sv.z + bv.z;
  v4.w = acc.w + dcc * sv.w + bv.w;
  size_t o4 = (size_t)node * 16 + sub;
  if (FINAL) {
    if (lane < 16) ((float4*)outp)[o4] = v4;
    float mx = fmaxf(fmaxf(v4.x, v4.y), fmaxf(v4.z, v4.w));
    #pragma unroll
    for (int o = 1; o < 16; o <<= 1) mx = fmaxf(mx, __shfl_xor(mx, o));
    float e = expf(v4.x - mx) + expf(v4.y - mx) + expf(v4.z - mx) + expf(v4.w - mx);
    #pragma unroll
    for (int o = 1; o < 16; o <<= 1) e += __shfl_xor(e, o);
    float ls = logf(e);
    float4 r4 = make_float4(v4.x - mx - ls, v4.y - mx - ls, v4.z - mx - ls, v4.w - mx - ls);
    if (lane < 16) ((float4*)(outp + (size_t)nN * 64))[o4] = r4;
  } else {
    v4.x = fmaxf(v4.x, 0.f); v4.y = fmaxf(v4.y, 0.f);
    v4.z = fmaxf(v4.z, 0.f); v4.w = fmaxf(v4.w, 0.f);
    if (lane < 16) ((float4*)outp)[o4] = v4;
  }
}

extern "C" void kernel_launch(void* const* d_in, const int* in_sizes, int n_in,
                              void* d_out, int out_size, void* d_ws, size_t ws_size,
                              hipStream_t stream) {
  const float* x  = (const float*)d_in[0];
  const int*   ei = (const int*)d_in[1];
  const int*   ec = (const int*)d_in[2];
  const float* W1 = (const float*)d_in[3];
  const float* b1 = (const float*)d_in[4];
  const float* W2 = (const float*)d_in[5];
  const float* b2 = (const float*)d_in[6];

  int nN = in_sizes[0] / 256;   // 100000
  int nE = in_sizes[2];         // 1600000
  const int* erow = ei;
  const int* ecol = ei + nE;
  int n64 = nN * 64;

  // ---- workspace layout (4B units) ----
  int* wsi = (int*)d_ws;
  int* mm   = wsi;                                  // 2
  int* gctr = wsi + 2;                              // 1
  unsigned long long* packed = (unsigned long long*)(wsi + 16);   // nN u64
  int*   rowptr = wsi + 16 + 2 * nN;
  float* dinv   = (float*)(rowptr + nN);
  int2*  srcw   = (int2*)(dinv + nN);               // even 4B offset -> 8B ok
  float* xw     = (float*)(srcw + nE);              // [nN,64]
  int*   rank   = (int*)xw;                         // aliases xw (dead at gemm1)
  float* h1     = xw + (size_t)n64;                 // [nN,64]
  float* outp   = (float*)d_out;

  // ---- CSR build + normalization ----
  k_zero<<<(nN + 255) / 256, 256, 0, stream>>>(packed, gctr, mm, nN);
  k_hist<<<(nE + 255) / 256, 256, 0, stream>>>(ecol, ec, packed, rank, nE);
  k_minmax<<<256, 256, 0, stream>>>(ec, nE, mm);
  k_base<<<(nN + 255) / 256, 256, 0, stream>>>(packed, mm, rowptr, dinv, gctr, nN);
  k_fill<<<(nE + 255) / 256, 256, 0, stream>>>(erow, ecol, ec, mm, rowptr, rank, srcw, nE);

  // ---- layer 1 ----
  k_gemm<256><<<(nN + 127) / 128, 256, 0, stream>>>(x, W1, xw, nN);
  k_agg<false><<<(nN + 3) / 4, 256, 0, stream>>>(rowptr, packed, srcw, dinv, xw, b1, h1, nN);

  // ---- layer 2 ----
  k_gemm<64><<<(nN + 127) / 128, 256, 0, stream>>>(h1, W2, xw, nN);
  k_agg<true><<<(nN + 3) / 4, 256, 0, stream>>>(rowptr, packed, srcw, dinv, xw, b2, outp, nN);
}

// Round 7
// 339.955 us; speedup vs baseline: 3.1158x; 1.1400x over previous
//
#include <hip/hip_runtime.h>
#include <climits>

#define CNT_SHIFT 44
#define SUM_MASK  ((1ULL << 44) - 1)

// ---------------- f32 -> bf16 (round-to-nearest-even) ----------------
__device__ __forceinline__ unsigned short f2bf(float f) {
  unsigned u = __float_as_uint(f);
  u = (u + 0x7fffu + ((u >> 16) & 1u)) >> 16;
  return (unsigned short)u;
}
__device__ __forceinline__ float bf_lo(unsigned d) { return __uint_as_float(d << 16); }
__device__ __forceinline__ float bf_hi(unsigned d) { return __uint_as_float(d & 0xffff0000u); }

// ---------------- async global->LDS 16B (no VGPR round-trip) ----------------
__device__ __forceinline__ void gload16(const float* g, float* l) {
  __builtin_amdgcn_global_load_lds(
      (const __attribute__((address_space(1))) void*)(g),
      (__attribute__((address_space(3))) void*)(l),
      16, 0, 0);
}

// ---------------- zero packed histogram, seed min/max ----------------
__global__ void k_zero(unsigned long long* __restrict__ packed,
                       int* __restrict__ gctr, int* __restrict__ mm, int n) {
  int i = blockIdx.x * blockDim.x + threadIdx.x;
  if (i < n) packed[i] = 0ULL;
  if (i == 0) { *gctr = 0; mm[0] = INT_MAX; mm[1] = INT_MIN; }
}

// ---------------- min/max: block-reduced, 2 atomics per block ----------------
__global__ void k_minmax(const int* __restrict__ ec, int n, int* __restrict__ mm) {
  __shared__ int smin[4], smax[4];
  int i = blockIdx.x * blockDim.x + threadIdx.x;
  int stride = gridDim.x * blockDim.x;
  int vmin = INT_MAX, vmax = INT_MIN;
  for (; i < n; i += stride) {
    int v = ec[i];
    vmin = min(vmin, v);
    vmax = max(vmax, v);
  }
  #pragma unroll
  for (int o = 32; o > 0; o >>= 1) {
    vmin = min(vmin, __shfl_xor(vmin, o));
    vmax = max(vmax, __shfl_xor(vmax, o));
  }
  int wid = threadIdx.x >> 6;
  if ((threadIdx.x & 63) == 0) { smin[wid] = vmin; smax[wid] = vmax; }
  __syncthreads();
  if (threadIdx.x == 0) {
    #pragma unroll
    for (int w = 1; w < 4; ++w) {
      vmin = min(vmin, smin[w]);
      vmax = max(vmax, smax[w]);
    }
    atomicMin(&mm[0], vmin);
    atomicMax(&mm[1], vmax);
  }
}

// ---------------- histogram: one packed u64 atomic per edge ----------------
__global__ void k_hist(const int* __restrict__ ecol, const int* __restrict__ ec,
                       unsigned long long* __restrict__ packed,
                       int* __restrict__ rank, int nE) {
  int i = blockIdx.x * blockDim.x + threadIdx.x;
  if (i >= nE) return;
  unsigned long long old =
      atomicAdd(&packed[ecol[i]], (1ULL << CNT_SHIFT) | (unsigned long long)(unsigned)ec[i]);
  rank[i] = (int)(old >> CNT_SHIFT);
}

// ---------------- rowptr scan + dinv from packed ----------------
__global__ void k_base(const unsigned long long* __restrict__ packed,
                       const int* __restrict__ mm,
                       int* __restrict__ rowptr, float* __restrict__ dinv,
                       int* __restrict__ gctr, int n) {
  int i = blockIdx.x * blockDim.x + threadIdx.x;
  int lane = threadIdx.x & 63;
  unsigned long long pk = (i < n) ? packed[i] : 0ULL;
  int v = (int)(pk >> CNT_SHIFT);
  if (i < n) {
    float mn = (float)mm[0];
    float rcp = 1.0f / (float)(mm[1] - mm[0]);
    float deg = ((float)(pk & SUM_MASK) - (float)v * mn) * rcp;
    dinv[i] = rsqrtf(deg + 1.0f);
  }
  int s = v;
  #pragma unroll
  for (int o = 1; o < 64; o <<= 1) {
    int t = __shfl_up(s, o);
    if (lane >= o) s += t;
  }
  int wtot = __shfl(s, 63);
  int base = 0;
  if (lane == 63) base = atomicAdd(gctr, wtot);
  base = __shfl(base, 63);
  if (i < n) rowptr[i] = base + s - v;
}

// ---------------- fill CSR without atomics: p = rowptr[c] + rank[e] --------
__global__ void k_fill(const int* __restrict__ erow, const int* __restrict__ ecol,
                       const int* __restrict__ ec, const int* __restrict__ mm,
                       const int* __restrict__ rowptr, const int* __restrict__ rank,
                       int2* __restrict__ srcw, int nE) {
  int e = blockIdx.x * blockDim.x + threadIdx.x;
  if (e >= nE) return;
  float mn = (float)mm[0];
  float rcp = 1.0f / (float)(mm[1] - mm[0]);
  float ew = ((float)ec[e] - mn) * rcp;
  int p = rowptr[ecol[e]] + rank[e];
  srcw[p] = make_int2(erow[e], __float_as_int(ew));
}

// ---------------- GEMM: [n,K]f32 x [K,64]f32 -> [n,64]bf16 -----------------
template<int K>
__global__ __launch_bounds__(256) void k_gemm(const float* __restrict__ A,
                                              const float* __restrict__ W,
                                              unsigned short* __restrict__ outh, int n) {
  constexpr int KSTEPS = K / 32;
  __shared__ float atile[2][128 * 32];
  __shared__ float wtile[2][32 * 64];
  const int tid = threadIdx.x;
  const int wv = tid >> 6;
  const int tr = tid >> 4, tc = tid & 15;
  const int rbase = blockIdx.x * 128;

  auto stageA = [&](int kt, int b) {
    #pragma unroll
    for (int r = 0; r < 4; ++r) {
      int f = r * 256 + tid;            // chunk index [0,1024)
      int row = f >> 3, c4s = f & 7;
      int c4 = c4s ^ (row & 7);         // pre-swizzled source chunk
      int gr = rbase + row; if (gr >= n) gr = n - 1;
      const float* g = A + (size_t)gr * K + kt * 32 + c4 * 4;
      float* l = &atile[b][(r * 256 + wv * 64) * 4];   // wave-uniform base
      gload16(g, l);
    }
  };
  auto stageW = [&](int kt, int b) {
    #pragma unroll
    for (int r = 0; r < 2; ++r) {
      int f = r * 256 + tid;            // chunk index [0,512)
      int krow = f >> 4, c4 = f & 15;
      const float* g = W + (size_t)(kt * 32 + krow) * 64 + c4 * 4;
      float* l = &wtile[b][(r * 256 + wv * 64) * 4];
      gload16(g, l);
    }
  };

  float4 acc[8];
  #pragma unroll
  for (int i = 0; i < 8; ++i) acc[i] = make_float4(0.f, 0.f, 0.f, 0.f);

  stageA(0, 0); stageW(0, 0);
  __syncthreads();
  int cur = 0;
  for (int kt = 0; kt < KSTEPS; ++kt) {
    if (kt + 1 < KSTEPS) { stageA(kt + 1, cur ^ 1); stageW(kt + 1, cur ^ 1); }
    const float* ab = atile[cur];
    const float* wb = wtile[cur];
    #pragma unroll
    for (int k4 = 0; k4 < 8; ++k4) {
      float4 wv0 = *(const float4*)&wb[(k4 * 4 + 0) * 64 + tc * 4];
      float4 wv1 = *(const float4*)&wb[(k4 * 4 + 1) * 64 + tc * 4];
      float4 wv2 = *(const float4*)&wb[(k4 * 4 + 2) * 64 + tc * 4];
      float4 wv3 = *(const float4*)&wb[(k4 * 4 + 3) * 64 + tc * 4];
      #pragma unroll
      for (int i = 0; i < 8; ++i) {
        int row = tr + 16 * i;
        float4 av = *(const float4*)&ab[row * 32 + ((k4 ^ (row & 7)) * 4)];
        acc[i].x = fmaf(av.x, wv0.x, acc[i].x);
        acc[i].y = fmaf(av.x, wv0.y, acc[i].y);
        acc[i].z = fmaf(av.x, wv0.z, acc[i].z);
        acc[i].w = fmaf(av.x, wv0.w, acc[i].w);
        acc[i].x = fmaf(av.y, wv1.x, acc[i].x);
        acc[i].y = fmaf(av.y, wv1.y, acc[i].y);
        acc[i].z = fmaf(av.y, wv1.z, acc[i].z);
        acc[i].w = fmaf(av.y, wv1.w, acc[i].w);
        acc[i].x = fmaf(av.z, wv2.x, acc[i].x);
        acc[i].y = fmaf(av.z, wv2.y, acc[i].y);
        acc[i].z = fmaf(av.z, wv2.z, acc[i].z);
        acc[i].w = fmaf(av.z, wv2.w, acc[i].w);
        acc[i].x = fmaf(av.w, wv3.x, acc[i].x);
        acc[i].y = fmaf(av.w, wv3.y, acc[i].y);
        acc[i].z = fmaf(av.w, wv3.z, acc[i].z);
        acc[i].w = fmaf(av.w, wv3.w, acc[i].w);
      }
    }
    __syncthreads();
    cur ^= 1;
  }
  #pragma unroll
  for (int i = 0; i < 8; ++i) {
    int row = rbase + tr + 16 * i;
    if (row < n) {
      ushort4 o4;
      o4.x = f2bf(acc[i].x); o4.y = f2bf(acc[i].y);
      o4.z = f2bf(acc[i].z); o4.w = f2bf(acc[i].w);
      *(ushort4*)&outh[(size_t)row * 64 + tc * 4] = o4;
    }
  }
}

// ---------------- aggregation: bf16 gathers, 8 rows in flight per wave ------
// Lane l: edge-group grp=l>>3, element-block sub=l&7 (elements sub*8..sub*8+7).
// One uint4 load = 16B = 8 bf16; 8 lanes cover a 128B row; 8 rows per instr.
// Partials combined via shfl_xor(8,16,32); epilogue on lanes 0-7.
template<bool FINAL>
__global__ void k_agg(const int* __restrict__ rowptr,
                      const unsigned long long* __restrict__ packed,
                      const int2* __restrict__ srcw, const float* __restrict__ dinv,
                      const unsigned short* __restrict__ xwh,  // [nN][64] bf16
                      const float* __restrict__ b,
                      float* __restrict__ outp, int nN) {
  int node = blockIdx.x * (blockDim.x >> 6) + (threadIdx.x >> 6);
  if (node >= nN) return;
  int lane = threadIdx.x & 63;
  int grp = lane >> 3, sub = lane & 7;
  float dc = dinv[node];
  const uint4* xw16 = (const uint4*)xwh;    // row stride = 8 chunks of 16B
  float acc[8] = {0.f, 0.f, 0.f, 0.f, 0.f, 0.f, 0.f, 0.f};
  int s = rowptr[node];
  int m = (int)(packed[node] >> CNT_SHIFT);
  for (int cb = 0; cb < m; cb += 64) {
    int take = min(64, m - cb);
    int rsrc = 0;
    float nrmv = 0.f;
    if (lane < take) {
      int2 rw = srcw[s + cb + lane];
      rsrc = rw.x;
      nrmv = dinv[rw.x] * __int_as_float(rw.y) * dc;
    }
    for (int j = 0; j < take; j += 8) {
      int jj = j + grp;                    // <= 63 always
      int r = __shfl(rsrc, jj);
      float nv = __shfl(nrmv, jj);         // 0 for padded jj >= take
      uint4 d = xw16[(size_t)r * 8 + sub];
      acc[0] = fmaf(nv, bf_lo(d.x), acc[0]);
      acc[1] = fmaf(nv, bf_hi(d.x), acc[1]);
      acc[2] = fmaf(nv, bf_lo(d.y), acc[2]);
      acc[3] = fmaf(nv, bf_hi(d.y), acc[3]);
      acc[4] = fmaf(nv, bf_lo(d.z), acc[4]);
      acc[5] = fmaf(nv, bf_hi(d.z), acc[5]);
      acc[6] = fmaf(nv, bf_lo(d.w), acc[6]);
      acc[7] = fmaf(nv, bf_hi(d.w), acc[7]);
    }
  }
  // combine the 8 edge-groups
  #pragma unroll
  for (int k = 0; k < 8; ++k) acc[k] += __shfl_xor(acc[k], 8);
  #pragma unroll
  for (int k = 0; k < 8; ++k) acc[k] += __shfl_xor(acc[k], 16);
  #pragma unroll
  for (int k = 0; k < 8; ++k) acc[k] += __shfl_xor(acc[k], 32);

  if (lane < 8) {
    uint4 d = xw16[(size_t)node * 8 + sub];     // self row (bf16)
    float sv[8] = {bf_lo(d.x), bf_hi(d.x), bf_lo(d.y), bf_hi(d.y),
                   bf_lo(d.z), bf_hi(d.z), bf_lo(d.w), bf_hi(d.w)};
    float dcc = dc * dc;
    float v[8];
    #pragma unroll
    for (int k = 0; k < 8; ++k) v[k] = acc[k] + dcc * sv[k] + b[sub * 8 + k];
    size_t o0 = (size_t)node * 64 + sub * 8;
    if (FINAL) {
      *(float4*)&outp[o0]     = make_float4(v[0], v[1], v[2], v[3]);
      *(float4*)&outp[o0 + 4] = make_float4(v[4], v[5], v[6], v[7]);
      float mx = v[0];
      #pragma unroll
      for (int k = 1; k < 8; ++k) mx = fmaxf(mx, v[k]);
      #pragma unroll
      for (int o = 1; o < 8; o <<= 1) mx = fmaxf(mx, __shfl_xor(mx, o));
      float e = 0.f;
      #pragma unroll
      for (int k = 0; k < 8; ++k) e += expf(v[k] - mx);
      #pragma unroll
      for (int o = 1; o < 8; o <<= 1) e += __shfl_xor(e, o);
      float ls = mx + logf(e);
      size_t o1 = (size_t)nN * 64 + o0;
      *(float4*)&outp[o1]     = make_float4(v[0] - ls, v[1] - ls, v[2] - ls, v[3] - ls);
      *(float4*)&outp[o1 + 4] = make_float4(v[4] - ls, v[5] - ls, v[6] - ls, v[7] - ls);
    } else {
      #pragma unroll
      for (int k = 0; k < 8; ++k) v[k] = fmaxf(v[k], 0.f);
      *(float4*)&outp[o0]     = make_float4(v[0], v[1], v[2], v[3]);
      *(float4*)&outp[o0 + 4] = make_float4(v[4], v[5], v[6], v[7]);
    }
  }
}

extern "C" void kernel_launch(void* const* d_in, const int* in_sizes, int n_in,
                              void* d_out, int out_size, void* d_ws, size_t ws_size,
                              hipStream_t stream) {
  const float* x  = (const float*)d_in[0];
  const int*   ei = (const int*)d_in[1];
  const int*   ec = (const int*)d_in[2];
  const float* W1 = (const float*)d_in[3];
  const float* b1 = (const float*)d_in[4];
  const float* W2 = (const float*)d_in[5];
  const float* b2 = (const float*)d_in[6];

  int nN = in_sizes[0] / 256;   // 100000
  int nE = in_sizes[2];         // 1600000
  const int* erow = ei;
  const int* ecol = ei + nE;
  int n64 = nN * 64;

  // ---- workspace layout (4B units) ----
  int* wsi = (int*)d_ws;
  int* mm   = wsi;                                  // 2
  int* gctr = wsi + 2;                              // 1
  unsigned long long* packed = (unsigned long long*)(wsi + 16);   // nN u64
  int*   rowptr = wsi + 16 + 2 * nN;
  float* dinv   = (float*)(rowptr + nN);
  int2*  srcw   = (int2*)(dinv + nN);               // 8B aligned
  unsigned short* xwh = (unsigned short*)(srcw + nE);  // [nN][64] bf16 (16B aligned)
  int*   rank   = (int*)xwh;                        // aliases xwh (dead at gemm1)
  float* h1     = (float*)(xwh + (size_t)n64);      // [nN,64] f32
  float* outp   = (float*)d_out;

  // ---- CSR build + normalization ----
  k_zero<<<(nN + 255) / 256, 256, 0, stream>>>(packed, gctr, mm, nN);
  k_hist<<<(nE + 255) / 256, 256, 0, stream>>>(ecol, ec, packed, rank, nE);
  k_minmax<<<256, 256, 0, stream>>>(ec, nE, mm);
  k_base<<<(nN + 255) / 256, 256, 0, stream>>>(packed, mm, rowptr, dinv, gctr, nN);
  k_fill<<<(nE + 255) / 256, 256, 0, stream>>>(erow, ecol, ec, mm, rowptr, rank, srcw, nE);

  // ---- layer 1 ----
  k_gemm<256><<<(nN + 127) / 128, 256, 0, stream>>>(x, W1, xwh, nN);
  k_agg<false><<<(nN + 3) / 4, 256, 0, stream>>>(rowptr, packed, srcw, dinv, xwh, b1, h1, nN);

  // ---- layer 2 ----
  k_gemm<64><<<(nN + 127) / 128, 256, 0, stream>>>(h1, W2, xwh, nN);
  k_agg<true><<<(nN + 3) / 4, 256, 0, stream>>>(rowptr, packed, srcw, dinv, xwh, b2, outp, nN);
}